// Round 18
// baseline (202.626 us; speedup 1.0000x reference)
//
#include <hip/hip_runtime.h>
#include <hip/hip_bf16.h>

// out[n,d] = b[d] + pk[n,d] + max_m ok[n,m,d]
//   pk = p @ Wp^T  (2048x1024,  K=1024)   -- small 128-tile kernel
//   ok = o @ Wo^T  (65536x1024, K=1024)   -- fused-convert 128^2 GEMM
// R18 = R17 + B double-buffer with the B(t+1) DMA issued MID-COMPUTE
// (between MFMA kk0 and kk1). The B wait folds into the tile-top VMCNT(0)
// with ~3/4-tile cover; the staging region shrinks to {vmcnt,cvt,write,lgkm}.
// FIFO ledger: entering staging(t) = [A(t):8 (older), B(t):4]; VMCNT(0)
// retires both (each issued >=3/4 tile ago). LDS 48KB -> 3 blocks/CU.

#define NN 2048
#define MM 32
#define CC 1024

typedef __attribute__((ext_vector_type(8))) __bf16 bf16x8;
typedef __attribute__((ext_vector_type(4))) float f32x4;
typedef __attribute__((ext_vector_type(8))) unsigned short u16x8;
typedef __attribute__((ext_vector_type(4))) unsigned short u16x4;

__device__ inline unsigned short f2bf(float f) {
  union { __hip_bfloat16 h; unsigned short u; } v;
  v.h = __float2bfloat16(f);
  return v.u;
}

__device__ inline void gload_lds16(const void* g, void* l) {
  __builtin_amdgcn_global_load_lds(
      (const __attribute__((address_space(1))) void*)g,
      (__attribute__((address_space(3))) void*)l, 16, 0, 0);
}

// ---- convert person_features + split W into Wp/Wo (bf16) ----
__global__ void conv_pw(const float* __restrict__ p, const float* __restrict__ W,
                        unsigned short* __restrict__ pd,
                        unsigned short* __restrict__ wp,
                        unsigned short* __restrict__ wo) {
  const int PG = (NN * CC) / 8;
  const int WG = (CC * 2 * CC) / 8;
  int i = blockIdx.x * blockDim.x + threadIdx.x;
  int stride = gridDim.x * blockDim.x;
  for (; i < PG + WG; i += stride) {
    if (i < PG) {
      const float4* s = reinterpret_cast<const float4*>(p) + (size_t)i * 2;
      float4 a = s[0], b = s[1];
      u16x8 r;
      r[0] = f2bf(a.x); r[1] = f2bf(a.y); r[2] = f2bf(a.z); r[3] = f2bf(a.w);
      r[4] = f2bf(b.x); r[5] = f2bf(b.y); r[6] = f2bf(b.z); r[7] = f2bf(b.w);
      *reinterpret_cast<u16x8*>(pd + (size_t)i * 8) = r;
    } else {
      int f = i - PG;
      int e = f * 8;
      int d = e >> 11;
      int cc = e & 2047;
      const float4* s = reinterpret_cast<const float4*>(W) + (size_t)f * 2;
      float4 a = s[0], b = s[1];
      u16x8 r;
      r[0] = f2bf(a.x); r[1] = f2bf(a.y); r[2] = f2bf(a.z); r[3] = f2bf(a.w);
      r[4] = f2bf(b.x); r[5] = f2bf(b.y); r[6] = f2bf(b.z); r[7] = f2bf(b.w);
      unsigned short* o = (cc < CC) ? (wp + (size_t)d * CC + cc)
                                    : (wo + (size_t)d * CC + (cc - CC));
      *reinterpret_cast<u16x8*>(o) = r;
    }
  }
}

// ---- small 128x128 GEMM for pk+b ----
__global__ void gemm_pk(const unsigned short* __restrict__ A,
                        const unsigned short* __restrict__ B,
                        const float* __restrict__ bvec,
                        float* __restrict__ out) {
  __shared__ unsigned short As[128 * 64];
  __shared__ unsigned short Bs[128 * 64];

  int nb = gridDim.x;
  int chunk = nb >> 3;
  int obid = blockIdx.x;
  int vb = (obid & 7) * chunk + (obid >> 3);
  int bcol = vb & 7;
  int brow = vb >> 3;

  int tid = threadIdx.x;
  int l = tid & 63;
  int wid = tid >> 6;
  int wr = wid >> 1, wc = wid & 1;
  int lr = l & 15;
  int lk = (l >> 4) << 3;

  const unsigned short* gA = A + (size_t)brow * 128 * CC;
  const unsigned short* gB = B + (size_t)bcol * 128 * CC;

  f32x4 acc[4][4] = {};

  for (int kt = 0; kt < 16; ++kt) {
    int k0 = kt * 64;
#pragma unroll
    for (int j = 0; j < 4; ++j) {
      int f = (j * 256 + tid) * 8;
      int r = f >> 6;
      int c = f & 63;
      gload_lds16(gA + (size_t)r * CC + k0 + c, &As[f]);
      gload_lds16(gB + (size_t)r * CC + k0 + c, &Bs[f]);
    }
    __syncthreads();
#pragma unroll
    for (int kk = 0; kk < 2; ++kk) {
      bf16x8 af[4], bfr[4];
#pragma unroll
      for (int mi = 0; mi < 4; ++mi)
        af[mi] = *reinterpret_cast<const bf16x8*>(
            &As[(wr * 64 + mi * 16 + lr) * 64 + kk * 32 + lk]);
#pragma unroll
      for (int ni = 0; ni < 4; ++ni)
        bfr[ni] = *reinterpret_cast<const bf16x8*>(
            &Bs[(wc * 64 + ni * 16 + lr) * 64 + kk * 32 + lk]);
#pragma unroll
      for (int mi = 0; mi < 4; ++mi)
#pragma unroll
        for (int ni = 0; ni < 4; ++ni)
          acc[mi][ni] = __builtin_amdgcn_mfma_f32_16x16x32_bf16(
              af[mi], bfr[ni], acc[mi][ni], 0, 0, 0);
    }
    __syncthreads();
  }

#pragma unroll
  for (int mi = 0; mi < 4; ++mi) {
    int row = brow * 128 + wr * 64 + mi * 16 + (l >> 4) * 4;
#pragma unroll
    for (int ni = 0; ni < 4; ++ni) {
      int col = bcol * 128 + wc * 64 + ni * 16 + lr;
      float bb = bvec[col];
#pragma unroll
      for (int r = 0; r < 4; ++r)
        out[(size_t)(row + r) * CC + col] = acc[mi][ni][r] + bb;
    }
  }
}

// ==================== 128x128 fused GEMM, B-dbuf mid-compute (R18) ==========
// LDS: A [128 x 64 bf16, 128B rows] @ 0 (16KB); Bbuf0 @ 16384; Bbuf1 @ 32768.
// Swizzle: LDS cell (row, chunk16B c) holds logical chunk c ^ (row&7).

#define BARRIER                                      \
  do {                                               \
    asm volatile("" ::: "memory");                   \
    __builtin_amdgcn_s_barrier();                    \
    asm volatile("" ::: "memory");                   \
  } while (0)

#define LGKM(n) asm volatile("s_waitcnt lgkmcnt(" #n ")" ::: "memory")
#define VMCNT(n) asm volatile("s_waitcnt vmcnt(" #n ")" ::: "memory")

// B stage into LDS byte offset bo: 128x64 bf16 = 16KB; 4 x gload_lds16/thr.
#define STAGE_B(bo, k0)                                                       \
  do {                                                                        \
    _Pragma("unroll") for (int j = 0; j < 4; ++j)                             \
        gload_lds16(gB + (size_t)(j * 32 + brr) * CC + (k0) + bsc,            \
                    lds + (bo) + (j * 256 + tid) * 16);                       \
  } while (0)

// A issue: instr j -> rows j*16 + (tid>>4), 16B col tid&15 (coalesced).
#define ISSUE_A(k0)                                                           \
  do {                                                                        \
    _Pragma("unroll") for (int j = 0; j < 8; ++j)                             \
        aL[j] = *reinterpret_cast<const float4*>(                             \
            gAf + (size_t)(j * 16 + arow0) * CC + (k0) + ac4 * 4);            \
  } while (0)

// cvt + swizzled ds_write_b64 into the A region
#define CVT_WRITE_A                                                           \
  do {                                                                        \
    _Pragma("unroll") for (int j = 0; j < 8; ++j) {                           \
      u16x4 r;                                                                \
      r[0] = f2bf(aL[j].x); r[1] = f2bf(aL[j].y);                             \
      r[2] = f2bf(aL[j].z); r[3] = f2bf(aL[j].w);                             \
      *reinterpret_cast<u16x4*>(lds + (j * 16 + arow0) * 128 + aswz) = r;     \
    }                                                                         \
  } while (0)

#define MFMA16X(AF)                                                           \
  do {                                                                        \
    __builtin_amdgcn_s_setprio(1);                                            \
    _Pragma("unroll") for (int mi = 0; mi < 4; ++mi)                          \
        _Pragma("unroll") for (int ni = 0; ni < 4; ++ni)                      \
            acc[mi][ni] = __builtin_amdgcn_mfma_f32_16x16x32_bf16(            \
                AF[mi], bfr[ni], acc[mi][ni], 0, 0, 0);                       \
    __builtin_amdgcn_s_setprio(0);                                            \
  } while (0)

__global__ __launch_bounds__(256, 3) void gemm_fused(
    const float* __restrict__ A,
    const unsigned short* __restrict__ B,
    const float* __restrict__ pkb,
    float* __restrict__ out) {
  __shared__ char lds[49152];

  int obid = blockIdx.x;                    // 4096 blocks
  int vb = (obid & 7) * 512 + (obid >> 3);  // XCD-contiguous (4096 % 8 == 0)
  int bcol = vb & 7;                        // 8 col tiles (col-fastest: L2 A-reuse)
  int brow = vb >> 3;                       // 512 row tiles

  int tid = threadIdx.x;
  int l = tid & 63;
  int wid = tid >> 6;
  int wr = wid >> 1;   // 0..1 (M half)
  int wc = wid & 1;    // 0..1 (N half)
  int lr = l & 15;
  int g = l >> 4;      // 0..3

  const float* gAf = A + (size_t)brow * 128 * CC;
  const unsigned short* gB = B + (size_t)bcol * 128 * CC;

  // B staging addressing
  int brr = tid >> 3;                            // 0..31
  int bsc = ((tid & 7) ^ ((tid >> 3) & 7)) * 8;  // inverse-swz source col

  // A reg-staging addressing: instr j -> row j*16+arow0, 16B f32 col ac4
  int arow0 = tid >> 4;                      // 0..15  (row&7 == arow0&7)
  int ac4 = tid & 15;
  int aswz = (((ac4 >> 1) ^ (arow0 & 7)) * 16) + (ac4 & 1) * 8;

  // fragment read bases: row R = (wr|wc)*64 + mi*16 + lr; chunk (kk*4+g)^(R&7)
  int axor = lr & 7;
  int a_k0 = (wr * 64 + lr) * 128 + ((g ^ axor) * 16);
  int a_k1 = (wr * 64 + lr) * 128 + (((4 + g) ^ axor) * 16);
  int b_k0 = (wc * 64 + lr) * 128 + ((g ^ axor) * 16);   // relative to B buf
  int b_k1 = (wc * 64 + lr) * 128 + (((4 + g) ^ axor) * 16);

  f32x4 acc[4][4] = {};
  bf16x8 af[4], af2[4], bfr[4];
  float4 aL[8];

  // prologue: A(0) [8, older], B(0)->buf0 [4]. Invariant at loop top holds.
  ISSUE_A(0);
  STAGE_B(16384, 0);

#pragma unroll 1
  for (int t = 0; t < 16; ++t) {
    int bofs = 16384 + ((t & 1) << 14);          // B buf for tile t
    int nbofs = 16384 + (((t + 1) & 1) << 14);   // B buf for tile t+1
    BARRIER;                 // all waves done reading A(t-1), Bbuf[nbofs]
    VMCNT(0);                // retire A(t)+B(t): both >= 3/4 tile old
    CVT_WRITE_A;             // A(t) f32 regs -> bf16 LDS (swizzled)
    if (t + 1 < 16) ISSUE_A((t + 1) * 64);  // A(t+1) [8]
    LGKM(0);                 // our ds_writes visible
    BARRIER;                 // A(t) + B(t) LDS ready for all waves
    // compute kk0 (kk-pipelined per R17), with B(t+1) DMA under MFMA kk0
#pragma unroll
    for (int mi = 0; mi < 4; ++mi)
      af[mi] = *(const bf16x8*)(lds + a_k0 + mi * 2048);
#pragma unroll
    for (int ni = 0; ni < 4; ++ni)
      bfr[ni] = *(const bf16x8*)(lds + bofs + b_k0 + ni * 2048);
#pragma unroll
    for (int mi = 0; mi < 4; ++mi)
      af2[mi] = *(const bf16x8*)(lds + a_k1 + mi * 2048);
    LGKM(4);                 // kk0's 8 reads done; af2's 4 still flying
    MFMA16X(af);             // kk0
    if (t + 1 < 16) STAGE_B(nbofs, (t + 1) * 64);  // B(t+1) DMA [4] under MFMA
#pragma unroll
    for (int ni = 0; ni < 4; ++ni)
      bfr[ni] = *(const bf16x8*)(lds + bofs + b_k1 + ni * 2048);
    LGKM(0);                 // af2 + bfr(kk1) ready
    MFMA16X(af2);            // kk1
  }

  // fused epilogue: max over 32 consecutive A-rows per n, + pkb
#pragma unroll
  for (int a = 0; a < 2; ++a) {
    int n = brow * 4 + wr * 2 + a;
#pragma unroll
    for (int ni = 0; ni < 4; ++ni) {
      float v = -3.402823466e38f;
#pragma unroll
      for (int mi = 2 * a; mi < 2 * a + 2; ++mi)
#pragma unroll
        for (int r = 0; r < 4; ++r) v = fmaxf(v, acc[mi][ni][r]);
      v = fmaxf(v, __shfl_xor(v, 16));
      v = fmaxf(v, __shfl_xor(v, 32));
      if (l < 16) {
        int col = bcol * 128 + wc * 64 + ni * 16 + l;
        out[(size_t)n * CC + col] = v + pkb[(size_t)n * CC + col];
      }
    }
  }
}

extern "C" void kernel_launch(void* const* d_in, const int* in_sizes, int n_in,
                              void* d_out, int out_size, void* d_ws, size_t ws_size,
                              hipStream_t stream) {
  const float* p = (const float*)d_in[0];   // (N, C, 1, 1)
  const float* o = (const float*)d_in[1];   // (N, M, C, 1, 1)
  const float* W = (const float*)d_in[5];   // (C, 2C)
  const float* b = (const float*)d_in[6];   // (C,)
  float* out = (float*)d_out;               // (N, C, 1, 1)

  char* ws = (char*)d_ws;
  unsigned short* p_bf  = (unsigned short*)ws;                 // 4 MB
  unsigned short* wp_bf = (unsigned short*)(ws + 4194304);     // 2 MB
  unsigned short* wo_bf = (unsigned short*)(ws + 6291456);     // 2 MB
  float*          pkb   = (float*)(ws + 8388608);              // 8 MB

  conv_pw<<<512, 256, 0, stream>>>(p, W, p_bf, wp_bf, wo_bf);
  gemm_pk<<<128, 256, 0, stream>>>(p_bf, wp_bf, b, pkb);
  // main: 512 row tiles x 8 col tiles = 4096 blocks, 256 threads
  gemm_fused<<<4096, 256, 0, stream>>>(o, wo_bf, pkb, out);
}

// Round 19
// 178.566 us; speedup vs baseline: 1.1347x; 1.1347x over previous
//
#include <hip/hip_runtime.h>
#include <hip/hip_bf16.h>

// out[n,d] = b[d] + pk[n,d] + max_m ok[n,m,d]
//   pk = p @ Wp^T  (2048x1024,  K=1024)   -- small 128-tile kernel
//   ok = o @ Wo^T  (65536x1024, K=1024)   -- fused-convert 128x256 GEMM
// R19 = R13's exact schedule at BM=128, BN=256, 512 thr (8 waves, 2Mx4N):
//   per-wave regs DROP (aL[4] not [8]) -> acc64+aL16+af16+bfr16+addr~14
//   fits the 128-reg cap of __launch_bounds__(512,4) = 4 waves/SIMD
//   = 2 blocks/CU, doubling MFMA work per tile period vs R13.
// LDS 48KB: A[128x64 bf16] @0 (16KB) + B[256x64 bf16] @16384 (32KB).
// Ledger (per thread): staging VMCNT(0) retires A(t)[4] (1 tile old);
// +B(t)[4]+A(t+1)[4]; VMCNT(4) retires B(t); t=15 VMCNT(0).

#define NN 2048
#define MM 32
#define CC 1024

typedef __attribute__((ext_vector_type(8))) __bf16 bf16x8;
typedef __attribute__((ext_vector_type(4))) float f32x4;
typedef __attribute__((ext_vector_type(8))) unsigned short u16x8;
typedef __attribute__((ext_vector_type(4))) unsigned short u16x4;

__device__ inline unsigned short f2bf(float f) {
  union { __hip_bfloat16 h; unsigned short u; } v;
  v.h = __float2bfloat16(f);
  return v.u;
}

__device__ inline void gload_lds16(const void* g, void* l) {
  __builtin_amdgcn_global_load_lds(
      (const __attribute__((address_space(1))) void*)g,
      (__attribute__((address_space(3))) void*)l, 16, 0, 0);
}

// ---- convert person_features + split W into Wp/Wo (bf16) ----
__global__ void conv_pw(const float* __restrict__ p, const float* __restrict__ W,
                        unsigned short* __restrict__ pd,
                        unsigned short* __restrict__ wp,
                        unsigned short* __restrict__ wo) {
  const int PG = (NN * CC) / 8;
  const int WG = (CC * 2 * CC) / 8;
  int i = blockIdx.x * blockDim.x + threadIdx.x;
  int stride = gridDim.x * blockDim.x;
  for (; i < PG + WG; i += stride) {
    if (i < PG) {
      const float4* s = reinterpret_cast<const float4*>(p) + (size_t)i * 2;
      float4 a = s[0], b = s[1];
      u16x8 r;
      r[0] = f2bf(a.x); r[1] = f2bf(a.y); r[2] = f2bf(a.z); r[3] = f2bf(a.w);
      r[4] = f2bf(b.x); r[5] = f2bf(b.y); r[6] = f2bf(b.z); r[7] = f2bf(b.w);
      *reinterpret_cast<u16x8*>(pd + (size_t)i * 8) = r;
    } else {
      int f = i - PG;
      int e = f * 8;
      int d = e >> 11;
      int cc = e & 2047;
      const float4* s = reinterpret_cast<const float4*>(W) + (size_t)f * 2;
      float4 a = s[0], b = s[1];
      u16x8 r;
      r[0] = f2bf(a.x); r[1] = f2bf(a.y); r[2] = f2bf(a.z); r[3] = f2bf(a.w);
      r[4] = f2bf(b.x); r[5] = f2bf(b.y); r[6] = f2bf(b.z); r[7] = f2bf(b.w);
      unsigned short* o = (cc < CC) ? (wp + (size_t)d * CC + cc)
                                    : (wo + (size_t)d * CC + (cc - CC));
      *reinterpret_cast<u16x8*>(o) = r;
    }
  }
}

// ---- small 128x128 GEMM for pk+b ----
__global__ void gemm_pk(const unsigned short* __restrict__ A,
                        const unsigned short* __restrict__ B,
                        const float* __restrict__ bvec,
                        float* __restrict__ out) {
  __shared__ unsigned short As[128 * 64];
  __shared__ unsigned short Bs[128 * 64];

  int nb = gridDim.x;
  int chunk = nb >> 3;
  int obid = blockIdx.x;
  int vb = (obid & 7) * chunk + (obid >> 3);
  int bcol = vb & 7;
  int brow = vb >> 3;

  int tid = threadIdx.x;
  int l = tid & 63;
  int wid = tid >> 6;
  int wr = wid >> 1, wc = wid & 1;
  int lr = l & 15;
  int lk = (l >> 4) << 3;

  const unsigned short* gA = A + (size_t)brow * 128 * CC;
  const unsigned short* gB = B + (size_t)bcol * 128 * CC;

  f32x4 acc[4][4] = {};

  for (int kt = 0; kt < 16; ++kt) {
    int k0 = kt * 64;
#pragma unroll
    for (int j = 0; j < 4; ++j) {
      int f = (j * 256 + tid) * 8;
      int r = f >> 6;
      int c = f & 63;
      gload_lds16(gA + (size_t)r * CC + k0 + c, &As[f]);
      gload_lds16(gB + (size_t)r * CC + k0 + c, &Bs[f]);
    }
    __syncthreads();
#pragma unroll
    for (int kk = 0; kk < 2; ++kk) {
      bf16x8 af[4], bfr[4];
#pragma unroll
      for (int mi = 0; mi < 4; ++mi)
        af[mi] = *reinterpret_cast<const bf16x8*>(
            &As[(wr * 64 + mi * 16 + lr) * 64 + kk * 32 + lk]);
#pragma unroll
      for (int ni = 0; ni < 4; ++ni)
        bfr[ni] = *reinterpret_cast<const bf16x8*>(
            &Bs[(wc * 64 + ni * 16 + lr) * 64 + kk * 32 + lk]);
#pragma unroll
      for (int mi = 0; mi < 4; ++mi)
#pragma unroll
        for (int ni = 0; ni < 4; ++ni)
          acc[mi][ni] = __builtin_amdgcn_mfma_f32_16x16x32_bf16(
              af[mi], bfr[ni], acc[mi][ni], 0, 0, 0);
    }
    __syncthreads();
  }

#pragma unroll
  for (int mi = 0; mi < 4; ++mi) {
    int row = brow * 128 + wr * 64 + mi * 16 + (l >> 4) * 4;
#pragma unroll
    for (int ni = 0; ni < 4; ++ni) {
      int col = bcol * 128 + wc * 64 + ni * 16 + lr;
      float bb = bvec[col];
#pragma unroll
      for (int r = 0; r < 4; ++r)
        out[(size_t)(row + r) * CC + col] = acc[mi][ni][r] + bb;
    }
  }
}

// ==================== 128x256 fused GEMM, 512 thr (R19) =====================
// LDS: A [128 x 64 bf16, 128B rows] @ 0 (16KB); B [256 x 64 bf16] @ 16384.
// Swizzle: LDS cell (row, chunk16B c) holds logical chunk c ^ (row&7).

#define BARRIER                                      \
  do {                                               \
    asm volatile("" ::: "memory");                   \
    __builtin_amdgcn_s_barrier();                    \
    asm volatile("" ::: "memory");                   \
  } while (0)

#define LGKM0 asm volatile("s_waitcnt lgkmcnt(0)" ::: "memory")
#define VMCNT(n) asm volatile("s_waitcnt vmcnt(" #n ")" ::: "memory")

// B stage: 256x64 bf16 = 32KB; 4 x gload_lds16/thread (512 thr).
// instr j -> row j*64 + (tid>>3), chunk tid&7; inverse-swizzled source.
#define STAGE_B(k0)                                                           \
  do {                                                                        \
    _Pragma("unroll") for (int j = 0; j < 4; ++j)                             \
        gload_lds16(gB + (size_t)(j * 64 + brr) * CC + (k0) + bsc,            \
                    lds + 16384 + ((j * 512 + tid) * 16));                    \
  } while (0)

// A issue: 128x64 f32 = 32KB; 4 x float4/thread (512 thr).
// instr j -> row j*32 + (tid>>4), 16B col tid&15 (lane-contiguous).
#define ISSUE_A(k0)                                                           \
  do {                                                                        \
    _Pragma("unroll") for (int j = 0; j < 4; ++j)                             \
        aL[j] = *reinterpret_cast<const float4*>(                             \
            gAf + (size_t)(j * 32 + arow0) * CC + (k0) + ac4 * 4);            \
  } while (0)

// cvt + swizzled ds_write_b64 into the A region
#define CVT_WRITE_A                                                           \
  do {                                                                        \
    _Pragma("unroll") for (int j = 0; j < 4; ++j) {                           \
      u16x4 r;                                                                \
      r[0] = f2bf(aL[j].x); r[1] = f2bf(aL[j].y);                             \
      r[2] = f2bf(aL[j].z); r[3] = f2bf(aL[j].w);                             \
      *reinterpret_cast<u16x4*>(lds + (j * 32 + arow0) * 128 + aswz) = r;     \
    }                                                                         \
  } while (0)

#define MFMA16X                                                               \
  do {                                                                        \
    __builtin_amdgcn_s_setprio(1);                                            \
    _Pragma("unroll") for (int mi = 0; mi < 4; ++mi)                          \
        _Pragma("unroll") for (int ni = 0; ni < 4; ++ni)                      \
            acc[mi][ni] = __builtin_amdgcn_mfma_f32_16x16x32_bf16(            \
                af[mi], bfr[ni], acc[mi][ni], 0, 0, 0);                       \
    __builtin_amdgcn_s_setprio(0);                                            \
  } while (0)

__global__ __launch_bounds__(512, 4) void gemm_fused(
    const float* __restrict__ A,
    const unsigned short* __restrict__ B,
    const float* __restrict__ pkb,
    float* __restrict__ out) {
  __shared__ char lds[49152];

  int obid = blockIdx.x;                    // 2048 blocks
  int vb = (obid & 7) * 256 + (obid >> 3);  // XCD-contiguous (2048 % 8 == 0)
  int bcol = vb & 3;                        // 4 col tiles of 256
  int brow = vb >> 2;                       // 512 row tiles of 128

  int tid = threadIdx.x;
  int l = tid & 63;
  int wid = tid >> 6;  // 0..7
  int wr = wid >> 2;   // 0..1 (M half, 64 rows)
  int wc = wid & 3;    // 0..3 (N quarter, 64 cols)
  int lr = l & 15;
  int g = l >> 4;      // 0..3

  const float* gAf = A + (size_t)brow * 128 * CC;
  const unsigned short* gB = B + (size_t)bcol * 256 * CC;

  // B staging addressing
  int brr = tid >> 3;                            // 0..63
  int bsc = ((tid & 7) ^ ((tid >> 3) & 7)) * 8;  // inverse-swz source col

  // A reg-staging addressing: instr j -> row j*32+arow0, 16B f32 col ac4
  int arow0 = tid >> 4;                      // 0..31  (row&7 == arow0&7)
  int ac4 = tid & 15;
  int aswz = (((ac4 >> 1) ^ (arow0 & 7)) * 16) + (ac4 & 1) * 8;

  // fragment read bases: A row = wr*64+mi*16+lr; B row = wc*64+ni*16+lr
  int axor = lr & 7;
  int a_k0 = (wr * 64 + lr) * 128 + ((g ^ axor) * 16);
  int a_k1 = (wr * 64 + lr) * 128 + (((4 + g) ^ axor) * 16);
  int b_k0 = 16384 + (wc * 64 + lr) * 128 + ((g ^ axor) * 16);
  int b_k1 = 16384 + (wc * 64 + lr) * 128 + (((4 + g) ^ axor) * 16);

  f32x4 acc[4][4] = {};
  bf16x8 af[4], bfr[4];
  float4 aL[4];

  // prologue: issue A(0) [4]; loop handles the rest.
  ISSUE_A(0);

#pragma unroll 1
  for (int t = 0; t < 16; ++t) {
    BARRIER;                 // all waves done reading tile t-1's LDS
    VMCNT(0);                // retire A(t) loads (issued one tile ago)
    CVT_WRITE_A;             // A(t) f32 regs -> bf16 LDS (swizzled)
    STAGE_B(t * 64);         // B(t) DMA [4 vmem]
    if (t + 1 < 16) ISSUE_A((t + 1) * 64);  // A(t+1) [4 vmem, younger]
    LGKM0;                   // our ds_writes visible
    if (t + 1 < 16) { VMCNT(4); } else { VMCNT(0); }  // retire B(t) DMA
    BARRIER;                 // LDS tile t ready for all waves
    // compute kk=0
#pragma unroll
    for (int mi = 0; mi < 4; ++mi)
      af[mi] = *(const bf16x8*)(lds + a_k0 + mi * 2048);
#pragma unroll
    for (int ni = 0; ni < 4; ++ni)
      bfr[ni] = *(const bf16x8*)(lds + b_k0 + ni * 2048);
    LGKM0;
    MFMA16X;
    // compute kk=1
#pragma unroll
    for (int mi = 0; mi < 4; ++mi)
      af[mi] = *(const bf16x8*)(lds + a_k1 + mi * 2048);
#pragma unroll
    for (int ni = 0; ni < 4; ++ni)
      bfr[ni] = *(const bf16x8*)(lds + b_k1 + ni * 2048);
    LGKM0;
    MFMA16X;
  }

  // fused epilogue: max over 32 consecutive A-rows per n, + pkb
#pragma unroll
  for (int a = 0; a < 2; ++a) {
    int n = brow * 4 + wr * 2 + a;
#pragma unroll
    for (int ni = 0; ni < 4; ++ni) {
      float v = -3.402823466e38f;
#pragma unroll
      for (int mi = 2 * a; mi < 2 * a + 2; ++mi)
#pragma unroll
        for (int r = 0; r < 4; ++r) v = fmaxf(v, acc[mi][ni][r]);
      v = fmaxf(v, __shfl_xor(v, 16));
      v = fmaxf(v, __shfl_xor(v, 32));
      if (l < 16) {
        int col = bcol * 256 + wc * 64 + ni * 16 + l;
        out[(size_t)n * CC + col] = v + pkb[(size_t)n * CC + col];
      }
    }
  }
}

extern "C" void kernel_launch(void* const* d_in, const int* in_sizes, int n_in,
                              void* d_out, int out_size, void* d_ws, size_t ws_size,
                              hipStream_t stream) {
  const float* p = (const float*)d_in[0];   // (N, C, 1, 1)
  const float* o = (const float*)d_in[1];   // (N, M, C, 1, 1)
  const float* W = (const float*)d_in[5];   // (C, 2C)
  const float* b = (const float*)d_in[6];   // (C,)
  float* out = (float*)d_out;               // (N, C, 1, 1)

  char* ws = (char*)d_ws;
  unsigned short* p_bf  = (unsigned short*)ws;                 // 4 MB
  unsigned short* wp_bf = (unsigned short*)(ws + 4194304);     // 2 MB
  unsigned short* wo_bf = (unsigned short*)(ws + 6291456);     // 2 MB
  float*          pkb   = (float*)(ws + 8388608);              // 8 MB

  conv_pw<<<512, 256, 0, stream>>>(p, W, p_bf, wp_bf, wo_bf);
  gemm_pk<<<128, 256, 0, stream>>>(p_bf, wp_bf, b, pkb);
  // main: 512 row tiles x 4 col tiles = 2048 blocks, 512 threads
  gemm_fused<<<2048, 512, 0, stream>>>(o, wo_bf, pkb, out);
}

// Round 20
// 176.842 us; speedup vs baseline: 1.1458x; 1.0097x over previous
//
#include <hip/hip_runtime.h>
#include <hip/hip_bf16.h>

// out[n,d] = b[d] + pk[n,d] + max_m ok[n,m,d]
//   pk = p @ Wp^T  (2048x1024,  K=1024)
//   ok = o @ Wo^T  (65536x1024, K=1024)
// R20 = R19 gemm_fused (unchanged) + single `prep` kernel replacing
// conv_pw+gemm_pk: blocks 0..511 convert Wo->bf16; blocks 512..639 run the
// pk GEMM with fused f32->bf16 convert of BOTH operands (p, Wp) using the
// proven reg-stage -> cvt -> swizzled ds_write pattern. One less launch,
// no conv dependency for pk.

#define NN 2048
#define MM 32
#define CC 1024

typedef __attribute__((ext_vector_type(8))) __bf16 bf16x8;
typedef __attribute__((ext_vector_type(4))) float f32x4;
typedef __attribute__((ext_vector_type(8))) unsigned short u16x8;
typedef __attribute__((ext_vector_type(4))) unsigned short u16x4;

__device__ inline unsigned short f2bf(float f) {
  union { __hip_bfloat16 h; unsigned short u; } v;
  v.h = __float2bfloat16(f);
  return v.u;
}

__device__ inline void gload_lds16(const void* g, void* l) {
  __builtin_amdgcn_global_load_lds(
      (const __attribute__((address_space(1))) void*)g,
      (__attribute__((address_space(3))) void*)l, 16, 0, 0);
}

#define BARRIER                                      \
  do {                                               \
    asm volatile("" ::: "memory");                   \
    __builtin_amdgcn_s_barrier();                    \
    asm volatile("" ::: "memory");                   \
  } while (0)

#define LGKM0 asm volatile("s_waitcnt lgkmcnt(0)" ::: "memory")
#define VMCNT(n) asm volatile("s_waitcnt vmcnt(" #n ")" ::: "memory")

// ==================== prep: Wo convert (512 blocks) + pk GEMM (128) =========
// pk part: 128x128 tile, single-buffer LDS (A=p @0, B=Wp @16384, both
// cvt'd in-kernel), R13-style drain-per-tile schedule, 4 waves (2x2).
__global__ __launch_bounds__(256, 2) void prep(
    const float* __restrict__ p,      // (N, C)
    const float* __restrict__ W,      // (C, 2C)
    const float* __restrict__ bvec,   // (C,)
    unsigned short* __restrict__ wo,  // out: Wo bf16 (C x C)
    float* __restrict__ pkb) {        // out: pk + b  (N x C)
  if (blockIdx.x < 512) {
    // ---- convert Wo = W[:, C:2C] -> bf16 ----
    int i = blockIdx.x * 256 + threadIdx.x;   // 0..131071, 8 elems each
    int e = i * 8;
    int d = e >> 10;          // row (C cols per Wo row)
    int c = e & 1023;
    const float4* s = reinterpret_cast<const float4*>(W + (size_t)d * 2048 + CC + c);
    float4 a = s[0], b = s[1];
    u16x8 r;
    r[0] = f2bf(a.x); r[1] = f2bf(a.y); r[2] = f2bf(a.z); r[3] = f2bf(a.w);
    r[4] = f2bf(b.x); r[5] = f2bf(b.y); r[6] = f2bf(b.z); r[7] = f2bf(b.w);
    *reinterpret_cast<u16x8*>(wo + (size_t)d * CC + c) = r;
    return;
  }

  // ---- pk GEMM with fused convert (blocks 512..639) ----
  __shared__ char lds[32768];
  int obid = blockIdx.x - 512;              // 0..127
  int vb = (obid & 7) * 16 + (obid >> 3);   // XCD-contiguous
  int bcol = vb & 7;                        // 8 col tiles
  int brow = vb >> 3;                       // 16 row tiles

  int tid = threadIdx.x;
  int l = tid & 63;
  int wid = tid >> 6;
  int wr = wid >> 1, wc = wid & 1;
  int lr = l & 15;
  int g = l >> 4;

  const float* gP = p + (size_t)brow * 128 * CC;
  const float* gW = W + (size_t)bcol * 128 * 2048;   // Wp = cols 0..C-1

  // staging: instr j -> row j*16+arow0, 16B f32 col ac4 (coalesced)
  int arow0 = tid >> 4;                      // 0..15
  int ac4 = tid & 15;
  int aswz = (((ac4 >> 1) ^ (arow0 & 7)) * 16) + (ac4 & 1) * 8;

  int axor = lr & 7;
  int a_k0 = (wr * 64 + lr) * 128 + ((g ^ axor) * 16);
  int a_k1 = (wr * 64 + lr) * 128 + (((4 + g) ^ axor) * 16);
  int b_k0 = 16384 + (wc * 64 + lr) * 128 + ((g ^ axor) * 16);
  int b_k1 = 16384 + (wc * 64 + lr) * 128 + (((4 + g) ^ axor) * 16);

  f32x4 acc[4][4] = {};
  bf16x8 af[4], bfr[4];
  float4 aL[8], bL[8];

#define ISSUE_P(k0)                                                           \
  do {                                                                        \
    _Pragma("unroll") for (int j = 0; j < 8; ++j)                             \
        aL[j] = *reinterpret_cast<const float4*>(                             \
            gP + (size_t)(j * 16 + arow0) * CC + (k0) + ac4 * 4);             \
  } while (0)
#define ISSUE_W(k0)                                                           \
  do {                                                                        \
    _Pragma("unroll") for (int j = 0; j < 8; ++j)                             \
        bL[j] = *reinterpret_cast<const float4*>(                             \
            gW + (size_t)(j * 16 + arow0) * 2048 + (k0) + ac4 * 4);           \
  } while (0)
#define CVT_WR(src, base)                                                     \
  do {                                                                        \
    _Pragma("unroll") for (int j = 0; j < 8; ++j) {                           \
      u16x4 r;                                                                \
      r[0] = f2bf(src[j].x); r[1] = f2bf(src[j].y);                           \
      r[2] = f2bf(src[j].z); r[3] = f2bf(src[j].w);                           \
      *reinterpret_cast<u16x4*>(lds + (base) + (j * 16 + arow0) * 128 + aswz) = r; \
    }                                                                         \
  } while (0)
#define PK_MFMA                                                               \
  do {                                                                        \
    _Pragma("unroll") for (int mi = 0; mi < 4; ++mi)                          \
        _Pragma("unroll") for (int ni = 0; ni < 4; ++ni)                      \
            acc[mi][ni] = __builtin_amdgcn_mfma_f32_16x16x32_bf16(            \
                af[mi], bfr[ni], acc[mi][ni], 0, 0, 0);                       \
  } while (0)

  ISSUE_P(0);
  ISSUE_W(0);

#pragma unroll 1
  for (int t = 0; t < 16; ++t) {
    BARRIER;
    VMCNT(0);                 // retire A(t)+B(t) (issued one tile ago)
    CVT_WR(aL, 0);
    CVT_WR(bL, 16384);
    if (t + 1 < 16) { ISSUE_P((t + 1) * 64); ISSUE_W((t + 1) * 64); }
    LGKM0;
    BARRIER;
#pragma unroll
    for (int mi = 0; mi < 4; ++mi)
      af[mi] = *(const bf16x8*)(lds + a_k0 + mi * 2048);
#pragma unroll
    for (int ni = 0; ni < 4; ++ni)
      bfr[ni] = *(const bf16x8*)(lds + b_k0 + ni * 2048);
    LGKM0;
    PK_MFMA;
#pragma unroll
    for (int mi = 0; mi < 4; ++mi)
      af[mi] = *(const bf16x8*)(lds + a_k1 + mi * 2048);
#pragma unroll
    for (int ni = 0; ni < 4; ++ni)
      bfr[ni] = *(const bf16x8*)(lds + b_k1 + ni * 2048);
    LGKM0;
    PK_MFMA;
  }

#pragma unroll
  for (int mi = 0; mi < 4; ++mi) {
    int row = brow * 128 + wr * 64 + mi * 16 + (l >> 4) * 4;
#pragma unroll
    for (int ni = 0; ni < 4; ++ni) {
      int col = bcol * 128 + wc * 64 + ni * 16 + lr;
      float bb = bvec[col];
#pragma unroll
      for (int r = 0; r < 4; ++r)
        pkb[(size_t)(row + r) * CC + col] = acc[mi][ni][r] + bb;
    }
  }
#undef ISSUE_P
#undef ISSUE_W
#undef CVT_WR
#undef PK_MFMA
}

// ==================== 128x256 fused GEMM, 512 thr (R19, unchanged) ==========
// LDS: A [128 x 64 bf16, 128B rows] @ 0 (16KB); B [256 x 64 bf16] @ 16384.
// Swizzle: LDS cell (row, chunk16B c) holds logical chunk c ^ (row&7).

#define STAGE_B(k0)                                                           \
  do {                                                                        \
    _Pragma("unroll") for (int j = 0; j < 4; ++j)                             \
        gload_lds16(gB + (size_t)(j * 64 + brr) * CC + (k0) + bsc,            \
                    lds + 16384 + ((j * 512 + tid) * 16));                    \
  } while (0)

#define ISSUE_A(k0)                                                           \
  do {                                                                        \
    _Pragma("unroll") for (int j = 0; j < 4; ++j)                             \
        aL[j] = *reinterpret_cast<const float4*>(                             \
            gAf + (size_t)(j * 32 + arow0) * CC + (k0) + ac4 * 4);            \
  } while (0)

#define CVT_WRITE_A                                                           \
  do {                                                                        \
    _Pragma("unroll") for (int j = 0; j < 4; ++j) {                           \
      u16x4 r;                                                                \
      r[0] = f2bf(aL[j].x); r[1] = f2bf(aL[j].y);                             \
      r[2] = f2bf(aL[j].z); r[3] = f2bf(aL[j].w);                             \
      *reinterpret_cast<u16x4*>(lds + (j * 32 + arow0) * 128 + aswz) = r;     \
    }                                                                         \
  } while (0)

#define MFMA16X                                                               \
  do {                                                                        \
    __builtin_amdgcn_s_setprio(1);                                            \
    _Pragma("unroll") for (int mi = 0; mi < 4; ++mi)                          \
        _Pragma("unroll") for (int ni = 0; ni < 4; ++ni)                      \
            acc[mi][ni] = __builtin_amdgcn_mfma_f32_16x16x32_bf16(            \
                af[mi], bfr[ni], acc[mi][ni], 0, 0, 0);                       \
    __builtin_amdgcn_s_setprio(0);                                            \
  } while (0)

__global__ __launch_bounds__(512, 4) void gemm_fused(
    const float* __restrict__ A,
    const unsigned short* __restrict__ B,
    const float* __restrict__ pkb,
    float* __restrict__ out) {
  __shared__ char lds[49152];

  int obid = blockIdx.x;                    // 2048 blocks
  int vb = (obid & 7) * 256 + (obid >> 3);  // XCD-contiguous (2048 % 8 == 0)
  int bcol = vb & 3;                        // 4 col tiles of 256
  int brow = vb >> 2;                       // 512 row tiles of 128

  int tid = threadIdx.x;
  int l = tid & 63;
  int wid = tid >> 6;  // 0..7
  int wr = wid >> 2;   // 0..1 (M half, 64 rows)
  int wc = wid & 3;    // 0..3 (N quarter, 64 cols)
  int lr = l & 15;
  int g = l >> 4;      // 0..3

  const float* gAf = A + (size_t)brow * 128 * CC;
  const unsigned short* gB = B + (size_t)bcol * 256 * CC;

  int brr = tid >> 3;                            // 0..63
  int bsc = ((tid & 7) ^ ((tid >> 3) & 7)) * 8;  // inverse-swz source col

  int arow0 = tid >> 4;                      // 0..31  (row&7 == arow0&7)
  int ac4 = tid & 15;
  int aswz = (((ac4 >> 1) ^ (arow0 & 7)) * 16) + (ac4 & 1) * 8;

  int axor = lr & 7;
  int a_k0 = (wr * 64 + lr) * 128 + ((g ^ axor) * 16);
  int a_k1 = (wr * 64 + lr) * 128 + (((4 + g) ^ axor) * 16);
  int b_k0 = 16384 + (wc * 64 + lr) * 128 + ((g ^ axor) * 16);
  int b_k1 = 16384 + (wc * 64 + lr) * 128 + (((4 + g) ^ axor) * 16);

  f32x4 acc[4][4] = {};
  bf16x8 af[4], bfr[4];
  float4 aL[4];

  ISSUE_A(0);

#pragma unroll 1
  for (int t = 0; t < 16; ++t) {
    BARRIER;
    VMCNT(0);                // retire A(t) loads (issued one tile ago)
    CVT_WRITE_A;
    STAGE_B(t * 64);         // B(t) DMA [4 vmem]
    if (t + 1 < 16) ISSUE_A((t + 1) * 64);
    LGKM0;
    if (t + 1 < 16) { VMCNT(4); } else { VMCNT(0); }
    BARRIER;
#pragma unroll
    for (int mi = 0; mi < 4; ++mi)
      af[mi] = *(const bf16x8*)(lds + a_k0 + mi * 2048);
#pragma unroll
    for (int ni = 0; ni < 4; ++ni)
      bfr[ni] = *(const bf16x8*)(lds + b_k0 + ni * 2048);
    LGKM0;
    MFMA16X;
#pragma unroll
    for (int mi = 0; mi < 4; ++mi)
      af[mi] = *(const bf16x8*)(lds + a_k1 + mi * 2048);
#pragma unroll
    for (int ni = 0; ni < 4; ++ni)
      bfr[ni] = *(const bf16x8*)(lds + b_k1 + ni * 2048);
    LGKM0;
    MFMA16X;
  }

  // fused epilogue: max over 32 consecutive A-rows per n, + pkb
#pragma unroll
  for (int a = 0; a < 2; ++a) {
    int n = brow * 4 + wr * 2 + a;
#pragma unroll
    for (int ni = 0; ni < 4; ++ni) {
      float v = -3.402823466e38f;
#pragma unroll
      for (int mi = 2 * a; mi < 2 * a + 2; ++mi)
#pragma unroll
        for (int r = 0; r < 4; ++r) v = fmaxf(v, acc[mi][ni][r]);
      v = fmaxf(v, __shfl_xor(v, 16));
      v = fmaxf(v, __shfl_xor(v, 32));
      if (l < 16) {
        int col = bcol * 256 + wc * 64 + ni * 16 + l;
        out[(size_t)n * CC + col] = v + pkb[(size_t)n * CC + col];
      }
    }
  }
}

extern "C" void kernel_launch(void* const* d_in, const int* in_sizes, int n_in,
                              void* d_out, int out_size, void* d_ws, size_t ws_size,
                              hipStream_t stream) {
  const float* p = (const float*)d_in[0];   // (N, C, 1, 1)
  const float* o = (const float*)d_in[1];   // (N, M, C, 1, 1)
  const float* W = (const float*)d_in[5];   // (C, 2C)
  const float* b = (const float*)d_in[6];   // (C,)
  float* out = (float*)d_out;               // (N, C, 1, 1)

  char* ws = (char*)d_ws;
  unsigned short* wo_bf = (unsigned short*)ws;             // 2 MB
  float*          pkb   = (float*)(ws + 2097152);          // 8 MB

  // prep: blocks 0..511 convert Wo; blocks 512..639 pk GEMM (fused cvt)
  prep<<<640, 256, 0, stream>>>(p, W, b, wo_bf, pkb);
  // main: 512 row tiles x 4 col tiles = 2048 blocks, 512 threads
  gemm_fused<<<2048, 512, 0, stream>>>(o, wo_bf, pkb, out);
}

// Round 21
// 169.216 us; speedup vs baseline: 1.1974x; 1.0451x over previous
//
#include <hip/hip_runtime.h>
#include <hip/hip_bf16.h>

// out[n,d] = b[d] + pk[n,d] + max_m ok[n,m,d]
//   pk = p @ Wp^T  (2048x1024,  K=1024)
//   ok = o @ Wo^T  (65536x1024, K=1024)
// R21 = R20 + B double-buffer at ZERO extra registers:
//   LDS 80KB (A 16K @0, Bbuf0 32K @16384, Bbuf1 32K @49152);
//   2 blocks x 80KB = 160KB = exact CU LDS -> occupancy preserved.
//   B(t+1) DMA issues in staging(t) into the alternate buffer; the loop's
//   ONLY vmem wait is VMCNT(0) at staging-top, retiring loads issued a
//   full tile (~1600cy) earlier. Single non-unrolled body + XOR buffer
//   toggle (uniform) -> avoids R14's macro-dup spill and R18's contention.

#define NN 2048
#define MM 32
#define CC 1024

typedef __attribute__((ext_vector_type(8))) __bf16 bf16x8;
typedef __attribute__((ext_vector_type(4))) float f32x4;
typedef __attribute__((ext_vector_type(8))) unsigned short u16x8;
typedef __attribute__((ext_vector_type(4))) unsigned short u16x4;

__device__ inline unsigned short f2bf(float f) {
  union { __hip_bfloat16 h; unsigned short u; } v;
  v.h = __float2bfloat16(f);
  return v.u;
}

__device__ inline void gload_lds16(const void* g, void* l) {
  __builtin_amdgcn_global_load_lds(
      (const __attribute__((address_space(1))) void*)g,
      (__attribute__((address_space(3))) void*)l, 16, 0, 0);
}

#define BARRIER                                      \
  do {                                               \
    asm volatile("" ::: "memory");                   \
    __builtin_amdgcn_s_barrier();                    \
    asm volatile("" ::: "memory");                   \
  } while (0)

#define LGKM0 asm volatile("s_waitcnt lgkmcnt(0)" ::: "memory")
#define VMCNT(n) asm volatile("s_waitcnt vmcnt(" #n ")" ::: "memory")

// ==================== prep: Wo convert (512 blocks) + pk GEMM (128) =========
__global__ __launch_bounds__(256, 2) void prep(
    const float* __restrict__ p,      // (N, C)
    const float* __restrict__ W,      // (C, 2C)
    const float* __restrict__ bvec,   // (C,)
    unsigned short* __restrict__ wo,  // out: Wo bf16 (C x C)
    float* __restrict__ pkb) {        // out: pk + b  (N x C)
  if (blockIdx.x < 512) {
    int i = blockIdx.x * 256 + threadIdx.x;
    int e = i * 8;
    int d = e >> 10;
    int c = e & 1023;
    const float4* s = reinterpret_cast<const float4*>(W + (size_t)d * 2048 + CC + c);
    float4 a = s[0], b = s[1];
    u16x8 r;
    r[0] = f2bf(a.x); r[1] = f2bf(a.y); r[2] = f2bf(a.z); r[3] = f2bf(a.w);
    r[4] = f2bf(b.x); r[5] = f2bf(b.y); r[6] = f2bf(b.z); r[7] = f2bf(b.w);
    *reinterpret_cast<u16x8*>(wo + (size_t)d * CC + c) = r;
    return;
  }

  __shared__ char lds[32768];
  int obid = blockIdx.x - 512;
  int vb = (obid & 7) * 16 + (obid >> 3);
  int bcol = vb & 7;
  int brow = vb >> 3;

  int tid = threadIdx.x;
  int l = tid & 63;
  int wid = tid >> 6;
  int wr = wid >> 1, wc = wid & 1;
  int lr = l & 15;
  int g = l >> 4;

  const float* gP = p + (size_t)brow * 128 * CC;
  const float* gW = W + (size_t)bcol * 128 * 2048;

  int arow0 = tid >> 4;
  int ac4 = tid & 15;
  int aswz = (((ac4 >> 1) ^ (arow0 & 7)) * 16) + (ac4 & 1) * 8;

  int axor = lr & 7;
  int a_k0 = (wr * 64 + lr) * 128 + ((g ^ axor) * 16);
  int a_k1 = (wr * 64 + lr) * 128 + (((4 + g) ^ axor) * 16);
  int b_k0 = 16384 + (wc * 64 + lr) * 128 + ((g ^ axor) * 16);
  int b_k1 = 16384 + (wc * 64 + lr) * 128 + (((4 + g) ^ axor) * 16);

  f32x4 acc[4][4] = {};
  bf16x8 af[4], bfr[4];
  float4 aL[8], bL[8];

#define ISSUE_P(k0)                                                           \
  do {                                                                        \
    _Pragma("unroll") for (int j = 0; j < 8; ++j)                             \
        aL[j] = *reinterpret_cast<const float4*>(                             \
            gP + (size_t)(j * 16 + arow0) * CC + (k0) + ac4 * 4);             \
  } while (0)
#define ISSUE_W(k0)                                                           \
  do {                                                                        \
    _Pragma("unroll") for (int j = 0; j < 8; ++j)                             \
        bL[j] = *reinterpret_cast<const float4*>(                             \
            gW + (size_t)(j * 16 + arow0) * 2048 + (k0) + ac4 * 4);           \
  } while (0)
#define CVT_WR(src, base)                                                     \
  do {                                                                        \
    _Pragma("unroll") for (int j = 0; j < 8; ++j) {                           \
      u16x4 r;                                                                \
      r[0] = f2bf(src[j].x); r[1] = f2bf(src[j].y);                           \
      r[2] = f2bf(src[j].z); r[3] = f2bf(src[j].w);                           \
      *reinterpret_cast<u16x4*>(lds + (base) + (j * 16 + arow0) * 128 + aswz) = r; \
    }                                                                         \
  } while (0)
#define PK_MFMA                                                               \
  do {                                                                        \
    _Pragma("unroll") for (int mi = 0; mi < 4; ++mi)                          \
        _Pragma("unroll") for (int ni = 0; ni < 4; ++ni)                      \
            acc[mi][ni] = __builtin_amdgcn_mfma_f32_16x16x32_bf16(            \
                af[mi], bfr[ni], acc[mi][ni], 0, 0, 0);                       \
  } while (0)

  ISSUE_P(0);
  ISSUE_W(0);

#pragma unroll 1
  for (int t = 0; t < 16; ++t) {
    BARRIER;
    VMCNT(0);
    CVT_WR(aL, 0);
    CVT_WR(bL, 16384);
    if (t + 1 < 16) { ISSUE_P((t + 1) * 64); ISSUE_W((t + 1) * 64); }
    LGKM0;
    BARRIER;
#pragma unroll
    for (int mi = 0; mi < 4; ++mi)
      af[mi] = *(const bf16x8*)(lds + a_k0 + mi * 2048);
#pragma unroll
    for (int ni = 0; ni < 4; ++ni)
      bfr[ni] = *(const bf16x8*)(lds + b_k0 + ni * 2048);
    LGKM0;
    PK_MFMA;
#pragma unroll
    for (int mi = 0; mi < 4; ++mi)
      af[mi] = *(const bf16x8*)(lds + a_k1 + mi * 2048);
#pragma unroll
    for (int ni = 0; ni < 4; ++ni)
      bfr[ni] = *(const bf16x8*)(lds + b_k1 + ni * 2048);
    LGKM0;
    PK_MFMA;
  }

#pragma unroll
  for (int mi = 0; mi < 4; ++mi) {
    int row = brow * 128 + wr * 64 + mi * 16 + (l >> 4) * 4;
#pragma unroll
    for (int ni = 0; ni < 4; ++ni) {
      int col = bcol * 128 + wc * 64 + ni * 16 + lr;
      float bb = bvec[col];
#pragma unroll
      for (int r = 0; r < 4; ++r)
        pkb[(size_t)(row + r) * CC + col] = acc[mi][ni][r] + bb;
    }
  }
#undef ISSUE_P
#undef ISSUE_W
#undef CVT_WR
#undef PK_MFMA
}

// ==================== 128x256 fused GEMM, B-dbuf (R21) ======================
// LDS: A [128x64 bf16, 128B rows] @ 0 (16KB); Bbuf0 @ 16384; Bbuf1 @ 49152.
// Swizzle: LDS cell (row, chunk16B c) holds logical chunk c ^ (row&7).

#define STAGE_B(bo, k0)                                                       \
  do {                                                                        \
    _Pragma("unroll") for (int j = 0; j < 4; ++j)                             \
        gload_lds16(gB + (size_t)(j * 64 + brr) * CC + (k0) + bsc,            \
                    lds + (bo) + ((j * 512 + tid) * 16));                     \
  } while (0)

#define ISSUE_A(k0)                                                           \
  do {                                                                        \
    _Pragma("unroll") for (int j = 0; j < 4; ++j)                             \
        aL[j] = *reinterpret_cast<const float4*>(                             \
            gAf + (size_t)(j * 32 + arow0) * CC + (k0) + ac4 * 4);            \
  } while (0)

#define CVT_WRITE_A                                                           \
  do {                                                                        \
    _Pragma("unroll") for (int j = 0; j < 4; ++j) {                           \
      u16x4 r;                                                                \
      r[0] = f2bf(aL[j].x); r[1] = f2bf(aL[j].y);                             \
      r[2] = f2bf(aL[j].z); r[3] = f2bf(aL[j].w);                             \
      *reinterpret_cast<u16x4*>(lds + (j * 32 + arow0) * 128 + aswz) = r;     \
    }                                                                         \
  } while (0)

#define MFMA16X                                                               \
  do {                                                                        \
    __builtin_amdgcn_s_setprio(1);                                            \
    _Pragma("unroll") for (int mi = 0; mi < 4; ++mi)                          \
        _Pragma("unroll") for (int ni = 0; ni < 4; ++ni)                      \
            acc[mi][ni] = __builtin_amdgcn_mfma_f32_16x16x32_bf16(            \
                af[mi], bfr[ni], acc[mi][ni], 0, 0, 0);                       \
    __builtin_amdgcn_s_setprio(0);                                            \
  } while (0)

__global__ __launch_bounds__(512, 4) void gemm_fused(
    const float* __restrict__ A,
    const unsigned short* __restrict__ B,
    const float* __restrict__ pkb,
    float* __restrict__ out) {
  __shared__ char lds[81920];

  int obid = blockIdx.x;                    // 2048 blocks
  int vb = (obid & 7) * 256 + (obid >> 3);  // XCD-contiguous (2048 % 8 == 0)
  int bcol = vb & 3;                        // 4 col tiles of 256
  int brow = vb >> 2;                       // 512 row tiles of 128

  int tid = threadIdx.x;
  int l = tid & 63;
  int wid = tid >> 6;  // 0..7
  int wr = wid >> 2;   // 0..1 (M half, 64 rows)
  int wc = wid & 3;    // 0..3 (N quarter, 64 cols)
  int lr = l & 15;
  int g = l >> 4;      // 0..3

  const float* gAf = A + (size_t)brow * 128 * CC;
  const unsigned short* gB = B + (size_t)bcol * 256 * CC;

  int brr = tid >> 3;                            // 0..63
  int bsc = ((tid & 7) ^ ((tid >> 3) & 7)) * 8;  // inverse-swz source col

  int arow0 = tid >> 4;                      // 0..31  (row&7 == arow0&7)
  int ac4 = tid & 15;
  int aswz = (((ac4 >> 1) ^ (arow0 & 7)) * 16) + (ac4 & 1) * 8;

  int axor = lr & 7;
  int a_k0 = (wr * 64 + lr) * 128 + ((g ^ axor) * 16);
  int a_k1 = (wr * 64 + lr) * 128 + (((4 + g) ^ axor) * 16);
  int b_k0r = (wc * 64 + lr) * 128 + ((g ^ axor) * 16);   // relative to B buf
  int b_k1r = (wc * 64 + lr) * 128 + (((4 + g) ^ axor) * 16);

  f32x4 acc[4][4] = {};
  bf16x8 af[4], bfr[4];
  float4 aL[4];

  // prologue: B(0) -> buf0, A(0) regs. Outstanding = [B(0):4, A(0):4].
  STAGE_B(16384, 0);
  ISSUE_A(0);

  int bcur = 16384;  // B buffer holding tile t (uniform)

#pragma unroll 1
  for (int t = 0; t < 16; ++t) {
    BARRIER;                 // tile t-1 LDS reads done (A + Bbuf[cur^32768])
    VMCNT(0);                // retire A(t)+B(t): issued a FULL tile ago
    CVT_WRITE_A;             // A(t) f32 regs -> bf16 LDS (swizzled)
    if (t + 1 < 16) {
      STAGE_B(bcur ^ 32768, (t + 1) * 64);  // B(t+1) DMA -> other buf [4]
      ISSUE_A((t + 1) * 64);                // A(t+1) [4]
    }
    LGKM0;                   // our ds_writes visible
    BARRIER;                 // A(t) + B(t) LDS ready for all waves
    // compute kk=0
#pragma unroll
    for (int mi = 0; mi < 4; ++mi)
      af[mi] = *(const bf16x8*)(lds + a_k0 + mi * 2048);
#pragma unroll
    for (int ni = 0; ni < 4; ++ni)
      bfr[ni] = *(const bf16x8*)(lds + bcur + b_k0r + ni * 2048);
    LGKM0;
    MFMA16X;
    // compute kk=1
#pragma unroll
    for (int mi = 0; mi < 4; ++mi)
      af[mi] = *(const bf16x8*)(lds + a_k1 + mi * 2048);
#pragma unroll
    for (int ni = 0; ni < 4; ++ni)
      bfr[ni] = *(const bf16x8*)(lds + bcur + b_k1r + ni * 2048);
    LGKM0;
    MFMA16X;
    bcur ^= 32768;
  }

  // fused epilogue: max over 32 consecutive A-rows per n, + pkb
#pragma unroll
  for (int a = 0; a < 2; ++a) {
    int n = brow * 4 + wr * 2 + a;
#pragma unroll
    for (int ni = 0; ni < 4; ++ni) {
      float v = -3.402823466e38f;
#pragma unroll
      for (int mi = 2 * a; mi < 2 * a + 2; ++mi)
#pragma unroll
        for (int r = 0; r < 4; ++r) v = fmaxf(v, acc[mi][ni][r]);
      v = fmaxf(v, __shfl_xor(v, 16));
      v = fmaxf(v, __shfl_xor(v, 32));
      if (l < 16) {
        int col = bcol * 256 + wc * 64 + ni * 16 + l;
        out[(size_t)n * CC + col] = v + pkb[(size_t)n * CC + col];
      }
    }
  }
}

extern "C" void kernel_launch(void* const* d_in, const int* in_sizes, int n_in,
                              void* d_out, int out_size, void* d_ws, size_t ws_size,
                              hipStream_t stream) {
  const float* p = (const float*)d_in[0];   // (N, C, 1, 1)
  const float* o = (const float*)d_in[1];   // (N, M, C, 1, 1)
  const float* W = (const float*)d_in[5];   // (C, 2C)
  const float* b = (const float*)d_in[6];   // (C,)
  float* out = (float*)d_out;               // (N, C, 1, 1)

  char* ws = (char*)d_ws;
  unsigned short* wo_bf = (unsigned short*)ws;             // 2 MB
  float*          pkb   = (float*)(ws + 2097152);          // 8 MB

  // prep: blocks 0..511 convert Wo; blocks 512..639 pk GEMM (fused cvt)
  prep<<<640, 256, 0, stream>>>(p, W, b, wo_bf, pkb);
  // main: 512 row tiles x 4 col tiles = 2048 blocks, 512 threads
  gemm_fused<<<2048, 512, 0, stream>>>(o, wo_bf, pkb, out);
}